// Round 1
// baseline (75.774 us; speedup 1.0000x reference)
//
#include <hip/hip_runtime.h>

// Laplacian pyramid, NUM_HIGH=3, img (16,3,512,512) f32, depthwise 5x5 kernel (3,1,5,5).
// reflect-101 padding; lax.conv = cross-correlation (no kernel flip).

#define B_ 16
#define C_ 3
#define H0 512
#define W0 512

__device__ __forceinline__ int reflect101(int t, int n) {
    t = (t < 0) ? -t : t;
    return (t >= n) ? (2 * n - 2 - t) : t;
}

// down[y][x] = sum_{dy,dx in 0..4} cur[r(2y+dy-2)][r(2x+dx-2)] * k[dy][dx]
__global__ __launch_bounds__(256) void down_kernel(
    const float* __restrict__ in, const float* __restrict__ kern,
    float* __restrict__ out, int H, int W)
{
    const int H2 = H >> 1, W2 = W >> 1;
    const int bc = blockIdx.z;
    const int c  = bc % C_;

    __shared__ float k[25];
    int tid = threadIdx.y * blockDim.x + threadIdx.x;
    if (tid < 25) k[tid] = kern[c * 25 + tid];
    __syncthreads();

    int x = blockIdx.x * blockDim.x + threadIdx.x;
    int y = blockIdx.y * blockDim.y + threadIdx.y;
    if (x >= W2 || y >= H2) return;

    const float* img = in + (size_t)bc * H * W;
    const int bx = 2 * x - 2, by = 2 * y - 2;

    float acc = 0.f;
    if (bx >= 0 && by >= 0 && bx + 4 < W && by + 4 < H) {
        const float* p = img + (size_t)by * W + bx;
        #pragma unroll
        for (int dy = 0; dy < 5; ++dy) {
            #pragma unroll
            for (int dx = 0; dx < 5; ++dx)
                acc += p[dx] * k[dy * 5 + dx];
            p += W;
        }
    } else {
        #pragma unroll
        for (int dy = 0; dy < 5; ++dy) {
            const float* row = img + (size_t)reflect101(by + dy, H) * W;
            #pragma unroll
            for (int dx = 0; dx < 5; ++dx)
                acc += row[reflect101(bx + dx, W)] * k[dy * 5 + dx];
        }
    }
    out[(size_t)bc * H2 * W2 + (size_t)y * W2 + x] = acc;
}

// Each thread: one 2x2 output block of pyr = cur - upsample(down).
// up taps: even coord -> down rows/cols {i-1, i, i+1} with k{0,2,4};
//          odd  coord -> down rows/cols {i, i+1}    with k{1,3}.
// Reflect in the 2H2-sized upsampled domain: down index -1 -> 1, H2 -> H2-1.
// Safe when pyr == cur (each thread reads cur only at its own 2x2 block).
__global__ __launch_bounds__(256) void upsub_kernel(
    const float* __restrict__ cur, const float* __restrict__ kern,
    const float* __restrict__ down, float* __restrict__ pyr,
    int H2, int W2)
{
    const int H = H2 * 2, W = W2 * 2;
    const int bc = blockIdx.z;
    const int c  = bc % C_;

    __shared__ float k[25];
    int tid = threadIdx.y * blockDim.x + threadIdx.x;
    if (tid < 25) k[tid] = kern[c * 25 + tid];
    __syncthreads();

    int x2 = blockIdx.x * blockDim.x + threadIdx.x;
    int y2 = blockIdx.y * blockDim.y + threadIdx.y;
    if (x2 >= W2 || y2 >= H2) return;

    const float* dn = down + (size_t)bc * H2 * W2;
    const float* cu = cur  + (size_t)bc * H * W;
    float*       py = pyr  + (size_t)bc * H * W;

    const int xm = (x2 == 0)      ? 1      : x2 - 1;
    const int xp = (x2 == W2 - 1) ? W2 - 1 : x2 + 1;
    const int ym = (y2 == 0)      ? 1      : y2 - 1;
    const int yp = (y2 == H2 - 1) ? H2 - 1 : y2 + 1;

    float d[3][3];
    {
        const float* r0 = dn + (size_t)ym * W2;
        const float* r1 = dn + (size_t)y2 * W2;
        const float* r2 = dn + (size_t)yp * W2;
        d[0][0] = r0[xm]; d[0][1] = r0[x2]; d[0][2] = r0[xp];
        d[1][0] = r1[xm]; d[1][1] = r1[x2]; d[1][2] = r1[xp];
        d[2][0] = r2[xm]; d[2][1] = r2[x2]; d[2][2] = r2[xp];
    }

    float uee = 0.f, ueo = 0.f, uoe = 0.f, uoo = 0.f;
    #pragma unroll
    for (int i = 0; i < 3; ++i) {
        #pragma unroll
        for (int j = 0; j < 3; ++j) {
            const float v = d[i][j];
            uee += v * k[(2 * i) * 5 + 2 * j];
            if (j)      ueo += v * k[(2 * i) * 5 + 2 * j - 1];
            if (i)      uoe += v * k[(2 * i - 1) * 5 + 2 * j];
            if (i && j) uoo += v * k[(2 * i - 1) * 5 + 2 * j - 1];
        }
    }

    const int y = 2 * y2, x = 2 * x2;
    const float2 c0 = *(const float2*)(cu + (size_t)y       * W + x);
    const float2 c1 = *(const float2*)(cu + (size_t)(y + 1) * W + x);
    float2 o0 = make_float2(c0.x - uee, c0.y - ueo);
    float2 o1 = make_float2(c1.x - uoe, c1.y - uoo);
    *(float2*)(py + (size_t)y       * W + x) = o0;
    *(float2*)(py + (size_t)(y + 1) * W + x) = o1;
}

extern "C" void kernel_launch(void* const* d_in, const int* in_sizes, int n_in,
                              void* d_out, int out_size, void* d_ws, size_t ws_size,
                              hipStream_t stream) {
    const float* img  = (const float*)d_in[0];
    const float* kern = (const float*)d_in[1];
    float* out = (float*)d_out;

    // Output layout: pyr0 (512^2) | pyr1 (256^2) | pyr2 (128^2) | pyr3=down3 (64^2), per (B,C).
    const size_t n0 = (size_t)B_ * C_ * 512 * 512;
    const size_t n1 = (size_t)B_ * C_ * 256 * 256;
    const size_t n2 = (size_t)B_ * C_ * 128 * 128;

    float* pyr0  = out;
    float* pyr1  = out + n0;
    float* pyr2  = out + n0 + n1;
    float* down3 = out + n0 + n1 + n2;

    // Park down1/down2 in the pyr1/pyr2 slots; later upsub overwrites them in place.
    float* down1 = pyr1;
    float* down2 = pyr2;

    const int BC = B_ * C_;
    const dim3 blk(64, 4, 1);
    auto grid_for = [&](int W2, int H2) {
        return dim3((W2 + 63) / 64, (H2 + 3) / 4, BC);
    };

    // Level 0: 512 -> down1 (256), pyr0
    down_kernel <<<grid_for(256, 256), blk, 0, stream>>>(img, kern, down1, 512, 512);
    upsub_kernel<<<grid_for(256, 256), blk, 0, stream>>>(img, kern, down1, pyr0, 256, 256);

    // Level 1: down1 (256) -> down2 (128), pyr1 (in place over down1)
    down_kernel <<<grid_for(128, 128), blk, 0, stream>>>(down1, kern, down2, 256, 256);
    upsub_kernel<<<grid_for(128, 128), blk, 0, stream>>>(down1, kern, down2, pyr1, 128, 128);

    // Level 2: down2 (128) -> down3 (64, final output), pyr2 (in place over down2)
    down_kernel <<<grid_for(64, 64), blk, 0, stream>>>(down2, kern, down3, 128, 128);
    upsub_kernel<<<grid_for(64, 64), blk, 0, stream>>>(down2, kern, down3, pyr2, 64, 64);
}

// Round 2
// 58.891 us; speedup vs baseline: 1.2867x; 1.2867x over previous
//
#include <hip/hip_runtime.h>

// Laplacian pyramid, NUM_HIGH=3, img (16,3,512,512) f32, depthwise 5x5 (3,1,5,5).
// reflect-101 input padding; lax.conv = cross-correlation (no flip).
// Fused per-level kernel: LDS-stage input tile -> down tile (w/ halo) -> pyr = cur - up.

#define B_ 16
#define C_ 3

// fused-kernel tile geometry
#define DX 64          // down interior tile width
#define DY 16          // down interior tile height
#define IW 136         // staged input tile width  = 2*(DX+2)+4
#define IH 39          // staged input tile height = 2*(DY+2)+4 (rows 2*dy0-4 .. 2*dy0+34)

__device__ __forceinline__ int reflect101(int t, int n) {
    t = (t < 0) ? -t : t;
    return (t >= n) ? (2 * n - 2 - t) : t;
}

__global__ __launch_bounds__(256) void lap_level_kernel(
    const float* __restrict__ in, const float* __restrict__ kern,
    float* __restrict__ down, float* __restrict__ pyr, int H, int W)
{
    const int H2 = H >> 1, W2 = W >> 1;
    const int bc  = blockIdx.z;
    const int c   = bc % C_;
    const int dx0 = blockIdx.x * DX;
    const int dy0 = blockIdx.y * DY;
    const int gx0 = 2 * dx0 - 4;      // multiple of 4 (dx0 mult of 64)
    const int gy0 = 2 * dy0 - 4;

    __shared__ float sIn[IH][IW];     // 21.2 KB
    __shared__ float sDn[DY + 2][68]; // 4.9 KB (66 used, pad to 68)
    __shared__ float sK[25];

    const int tid = threadIdx.x;
    if (tid < 25) sK[tid] = kern[c * 25 + tid];

    const float* src = in + (size_t)bc * H * W;

    // ---- stage input tile (float4-coalesced; scalar reflect at borders) ----
    for (int s = tid; s < IH * (IW / 4); s += 256) {
        const int r  = s / (IW / 4);
        const int q  = s - r * (IW / 4);
        const int gy = gy0 + r;
        const int gx = gx0 + 4 * q;
        const float* row = src + (size_t)reflect101(gy, H) * W;
        float4 v;
        if (gx >= 0 && gx + 3 < W) {
            v = *(const float4*)(row + gx);
        } else {
            v.x = row[reflect101(gx + 0, W)];
            v.y = row[reflect101(gx + 1, W)];
            v.z = row[reflect101(gx + 2, W)];
            v.w = row[reflect101(gx + 3, W)];
        }
        *(float4*)&sIn[r][4 * q] = v;
    }
    __syncthreads();

    // ---- down phase: 33x18 position-pairs, float4 LDS reads ----
    // pair p -> positions (dr, 2*pc) and (dr, 2*pc+1) in the 66x18 halo tile
    for (int p = tid; p < 33 * (DY + 2); p += 256) {
        const int dr = p / 33;
        const int pc = p - dr * 33;
        float accA = 0.f, accB = 0.f;
        #pragma unroll
        for (int i = 0; i < 5; ++i) {
            const float4 v0 = *(const float4*)&sIn[2 * dr + i][4 * pc];
            const float4 v1 = *(const float4*)&sIn[2 * dr + i][4 * pc + 4];
            const float k0 = sK[i * 5 + 0], k1 = sK[i * 5 + 1], k2 = sK[i * 5 + 2],
                        k3 = sK[i * 5 + 3], k4 = sK[i * 5 + 4];
            accA += v0.x * k0 + v0.y * k1 + v0.z * k2 + v0.w * k3 + v1.x * k4;
            accB += v0.z * k0 + v0.w * k1 + v1.x * k2 + v1.y * k3 + v1.z * k4;
        }
        sDn[dr][2 * pc]     = accA;
        sDn[dr][2 * pc + 1] = accB;
    }
    __syncthreads();

    // ---- write down interior (coalesced scalar) ----
    {
        float* dst = down + (size_t)bc * H2 * W2;
        for (int s = tid; s < DX * DY; s += 256) {
            const int r = s >> 6;
            const int q = s & 63;
            dst[(size_t)(dy0 + r) * W2 + dx0 + q] = sDn[r + 1][q + 1];
        }
    }

    // ---- upsub phase: 512 pairs, each = 2 down positions -> 2x4 pyr block ----
    for (int pp = tid; pp < 512; pp += 256) {
        const int pr  = pp >> 5;            // 0..15
        const int pq  = pp & 31;            // 0..31
        const int gdy = dy0 + pr;           // global down row of this position
        const int gxA = dx0 + 2 * pq;       // global down col of position A

        // up's boundary semantics: down[-1] -> down[1], down[H2] -> down[H2-1]
        const int r0 = (gdy == 0)      ? pr + 2 : pr;
        const int r2 = (gdy == H2 - 1) ? pr     : pr + 2;
        const int rows[3] = { r0, pr + 1, r2 };
        const bool leftE  = (gxA == 0);
        const bool rightE = (gxA + 1 == W2 - 1);

        float uee_a = 0, ueo_a = 0, uoe_a = 0, uoo_a = 0;
        float uee_b = 0, ueo_b = 0, uoe_b = 0, uoo_b = 0;
        #pragma unroll
        for (int i = 0; i < 3; ++i) {
            const float2 va = *(const float2*)&sDn[rows[i]][2 * pq];
            const float2 vb = *(const float2*)&sDn[rows[i]][2 * pq + 2];
            float aL = va.x, aC = va.y, aR = vb.x;
            float bL = va.y, bC = vb.x, bR = vb.y;
            if (leftE)  aL = aR;   // down[-1]   == down[1]
            if (rightE) bR = bC;   // down[W2]   == down[W2-1]
            uee_a += aL * sK[10 * i + 0] + aC * sK[10 * i + 2] + aR * sK[10 * i + 4];
            ueo_a += aC * sK[10 * i + 1] + aR * sK[10 * i + 3];
            uee_b += bL * sK[10 * i + 0] + bC * sK[10 * i + 2] + bR * sK[10 * i + 4];
            ueo_b += bC * sK[10 * i + 1] + bR * sK[10 * i + 3];
            if (i) {
                uoe_a += aL * sK[10 * i - 5] + aC * sK[10 * i - 3] + aR * sK[10 * i - 1];
                uoo_a += aC * sK[10 * i - 4] + aR * sK[10 * i - 2];
                uoe_b += bL * sK[10 * i - 5] + bC * sK[10 * i - 3] + bR * sK[10 * i - 1];
                uoo_b += bC * sK[10 * i - 4] + bR * sK[10 * i - 2];
            }
        }

        const int ly = 2 * pr + 4;          // sIn row of pyr even row
        const int lx = 4 * pq + 4;
        const float4 c0 = *(const float4*)&sIn[ly][lx];
        const float4 c1 = *(const float4*)&sIn[ly + 1][lx];
        const float4 o0 = make_float4(c0.x - uee_a, c0.y - ueo_a, c0.z - uee_b, c0.w - ueo_b);
        const float4 o1 = make_float4(c1.x - uoe_a, c1.y - uoo_a, c1.z - uoe_b, c1.w - uoo_b);
        float* py = pyr + (size_t)bc * H * W;
        const size_t base = (size_t)(2 * gdy) * W + (2 * dx0 + 4 * pq);
        *(float4*)(py + base)     = o0;
        *(float4*)(py + base + W) = o1;
    }
}

// ---------------- fallback (no-workspace) kernels, from R1 ----------------
__global__ __launch_bounds__(256) void down_kernel(
    const float* __restrict__ in, const float* __restrict__ kern,
    float* __restrict__ out, int H, int W)
{
    const int H2 = H >> 1, W2 = W >> 1;
    const int bc = blockIdx.z;
    const int c  = bc % C_;
    __shared__ float k[25];
    int tid = threadIdx.y * blockDim.x + threadIdx.x;
    if (tid < 25) k[tid] = kern[c * 25 + tid];
    __syncthreads();
    int x = blockIdx.x * blockDim.x + threadIdx.x;
    int y = blockIdx.y * blockDim.y + threadIdx.y;
    if (x >= W2 || y >= H2) return;
    const float* img = in + (size_t)bc * H * W;
    const int bx = 2 * x - 2, by = 2 * y - 2;
    float acc = 0.f;
    if (bx >= 0 && by >= 0 && bx + 4 < W && by + 4 < H) {
        const float* p = img + (size_t)by * W + bx;
        #pragma unroll
        for (int dy = 0; dy < 5; ++dy) {
            #pragma unroll
            for (int dx = 0; dx < 5; ++dx) acc += p[dx] * k[dy * 5 + dx];
            p += W;
        }
    } else {
        #pragma unroll
        for (int dy = 0; dy < 5; ++dy) {
            const float* row = img + (size_t)reflect101(by + dy, H) * W;
            #pragma unroll
            for (int dx = 0; dx < 5; ++dx) acc += row[reflect101(bx + dx, W)] * k[dy * 5 + dx];
        }
    }
    out[(size_t)bc * H2 * W2 + (size_t)y * W2 + x] = acc;
}

__global__ __launch_bounds__(256) void upsub_kernel(
    const float* __restrict__ cur, const float* __restrict__ kern,
    const float* __restrict__ down, float* __restrict__ pyr,
    int H2, int W2)
{
    const int H = H2 * 2, W = W2 * 2;
    const int bc = blockIdx.z;
    const int c  = bc % C_;
    __shared__ float k[25];
    int tid = threadIdx.y * blockDim.x + threadIdx.x;
    if (tid < 25) k[tid] = kern[c * 25 + tid];
    __syncthreads();
    int x2 = blockIdx.x * blockDim.x + threadIdx.x;
    int y2 = blockIdx.y * blockDim.y + threadIdx.y;
    if (x2 >= W2 || y2 >= H2) return;
    const float* dn = down + (size_t)bc * H2 * W2;
    const float* cu = cur  + (size_t)bc * H * W;
    float*       py = pyr  + (size_t)bc * H * W;
    const int xm = (x2 == 0)      ? 1      : x2 - 1;
    const int xp = (x2 == W2 - 1) ? W2 - 1 : x2 + 1;
    const int ym = (y2 == 0)      ? 1      : y2 - 1;
    const int yp = (y2 == H2 - 1) ? H2 - 1 : y2 + 1;
    float d[3][3];
    {
        const float* r0 = dn + (size_t)ym * W2;
        const float* r1 = dn + (size_t)y2 * W2;
        const float* r2 = dn + (size_t)yp * W2;
        d[0][0] = r0[xm]; d[0][1] = r0[x2]; d[0][2] = r0[xp];
        d[1][0] = r1[xm]; d[1][1] = r1[x2]; d[1][2] = r1[xp];
        d[2][0] = r2[xm]; d[2][1] = r2[x2]; d[2][2] = r2[xp];
    }
    float uee = 0.f, ueo = 0.f, uoe = 0.f, uoo = 0.f;
    #pragma unroll
    for (int i = 0; i < 3; ++i) {
        #pragma unroll
        for (int j = 0; j < 3; ++j) {
            const float v = d[i][j];
            uee += v * k[(2 * i) * 5 + 2 * j];
            if (j)      ueo += v * k[(2 * i) * 5 + 2 * j - 1];
            if (i)      uoe += v * k[(2 * i - 1) * 5 + 2 * j];
            if (i && j) uoo += v * k[(2 * i - 1) * 5 + 2 * j - 1];
        }
    }
    const int y = 2 * y2, x = 2 * x2;
    const float2 c0 = *(const float2*)(cu + (size_t)y       * W + x);
    const float2 c1 = *(const float2*)(cu + (size_t)(y + 1) * W + x);
    *(float2*)(py + (size_t)y       * W + x) = make_float2(c0.x - uee, c0.y - ueo);
    *(float2*)(py + (size_t)(y + 1) * W + x) = make_float2(c1.x - uoe, c1.y - uoo);
}

extern "C" void kernel_launch(void* const* d_in, const int* in_sizes, int n_in,
                              void* d_out, int out_size, void* d_ws, size_t ws_size,
                              hipStream_t stream) {
    const float* img  = (const float*)d_in[0];
    const float* kern = (const float*)d_in[1];
    float* out = (float*)d_out;

    const size_t n0 = (size_t)B_ * C_ * 512 * 512;
    const size_t n1 = (size_t)B_ * C_ * 256 * 256;
    const size_t n2 = (size_t)B_ * C_ * 128 * 128;

    float* pyr0  = out;
    float* pyr1  = out + n0;
    float* pyr2  = out + n0 + n1;
    float* down3 = out + n0 + n1 + n2;

    const int BC = B_ * C_;
    auto grid_for = [&](int W2, int H2) { return dim3(W2 / DX, H2 / DY, BC); };

    const size_t need = (n1 + n2) * sizeof(float);
    if (ws_size >= need) {
        // down1/down2 live in workspace -> no in-place aliasing, full fusion.
        float* down1 = (float*)d_ws;
        float* down2 = down1 + n1;
        lap_level_kernel<<<grid_for(256, 256), 256, 0, stream>>>(img,   kern, down1, pyr0, 512, 512);
        lap_level_kernel<<<grid_for(128, 128), 256, 0, stream>>>(down1, kern, down2, pyr1, 256, 256);
        lap_level_kernel<<<grid_for( 64,  64), 256, 0, stream>>>(down2, kern, down3, pyr2, 128, 128);
    } else {
        // fallback: fuse only level 0 (img is read-only, down1 parked in pyr1 slot);
        // levels 1/2 use the R1 two-kernel in-place-safe scheme.
        float* down1 = pyr1;
        float* down2 = pyr2;
        lap_level_kernel<<<grid_for(256, 256), 256, 0, stream>>>(img, kern, down1, pyr0, 512, 512);
        const dim3 blk(64, 4, 1);
        auto g2 = [&](int W2, int H2) { return dim3((W2 + 63) / 64, (H2 + 3) / 4, BC); };
        down_kernel <<<g2(128, 128), blk, 0, stream>>>(down1, kern, down2, 256, 256);
        upsub_kernel<<<g2(128, 128), blk, 0, stream>>>(down1, kern, down2, pyr1, 128, 128);
        down_kernel <<<g2( 64,  64), blk, 0, stream>>>(down2, kern, down3, 128, 128);
        upsub_kernel<<<g2( 64,  64), blk, 0, stream>>>(down2, kern, down3, pyr2, 64, 64);
    }
}

// Round 3
// 53.686 us; speedup vs baseline: 1.4114x; 1.0970x over previous
//
#include <hip/hip_runtime.h>

// Laplacian pyramid, NUM_HIGH=3, img (16,3,512,512) f32, depthwise 5x5 (3,1,5,5).
// reflect-101 input padding; lax.conv = cross-correlation (no flip).
// Fused per-level kernel, pow2 lane mappings, taps in SGPRs, down-write folded into upsub.

#define B_ 16
#define C_ 3

__device__ __forceinline__ int reflect101(int t, int n) {
    t = (t < 0) ? -t : t;
    return (t >= n) ? (2 * n - 2 - t) : t;
}

// Tile: down interior DX x DY, down halo (DX+2) x (DY+2), input stage (2DX+8) x (2DY+7).
template<int DX, int DY, int LOG2MQ>
__global__ __launch_bounds__(256, 6) void lap_level_t(
    const float* __restrict__ in, const float* __restrict__ kern,
    float* __restrict__ down, float* __restrict__ pyr, int H, int W)
{
    constexpr int IW  = 2 * DX + 8;       // staged input width (floats)
    constexpr int IH  = 2 * DY + 7;       // staged input rows
    constexpr int MQ  = DX / 2;           // main float4 cols per row (pow2), == 1<<LOG2MQ
    constexpr int SDW = DX + 4;           // sDn padded width (66->68, 34->36)

    __shared__ float sIn[IH][IW];
    __shared__ float sDn[DY + 2][SDW];

    const int H2 = H >> 1, W2 = W >> 1;
    const int bc  = blockIdx.z;
    const int c   = bc % C_;
    const int dx0 = blockIdx.x * DX;
    const int dy0 = blockIdx.y * DY;
    const int gx0 = 2 * dx0 - 4;
    const int gy0 = 2 * dy0 - 4;
    const int tid = threadIdx.x;

    // taps: uniform loads -> SGPRs
    float kk[25];
    #pragma unroll
    for (int i = 0; i < 25; ++i) kk[i] = kern[c * 25 + i];

    const float* src = in + (size_t)bc * H * W;

    // ---------------- stage input tile ----------------
    {
        const int q  = tid & (MQ - 1);             // per-lane constant
        const int gx = gx0 + 4 * q;
        const bool colOK = (gx >= 0) && (gx + 3 < W);
        int cx0 = 0, cx1 = 0, cx2 = 0, cx3 = 0;
        if (!colOK) {
            cx0 = reflect101(gx + 0, W); cx1 = reflect101(gx + 1, W);
            cx2 = reflect101(gx + 2, W); cx3 = reflect101(gx + 3, W);
        }
        constexpr int RSTEP = 256 >> LOG2MQ;
        for (int r = tid >> LOG2MQ; r < IH; r += RSTEP) {
            const float* row = src + (size_t)reflect101(gy0 + r, H) * W;
            float4 v;
            if (colOK) v = *(const float4*)(row + gx);
            else       v = make_float4(row[cx0], row[cx1], row[cx2], row[cx3]);
            *(float4*)&sIn[r][4 * q] = v;
        }
        // side cols 2DX .. 2DX+7 (two float4 per row)
        if (tid < 2 * IH) {
            const int r   = tid >> 1;
            const int q2  = MQ + (tid & 1);
            const int gx2 = gx0 + 4 * q2;
            const float* row = src + (size_t)reflect101(gy0 + r, H) * W;
            float4 v;
            if (gx2 >= 0 && gx2 + 3 < W) v = *(const float4*)(row + gx2);
            else v = make_float4(row[reflect101(gx2 + 0, W)], row[reflect101(gx2 + 1, W)],
                                 row[reflect101(gx2 + 2, W)], row[reflect101(gx2 + 3, W)]);
            *(float4*)&sIn[r][4 * q2] = v;
        }
    }
    __syncthreads();

    // ---------------- down phase (incl. halo) ----------------
    // sDn row r = global down row dy0-1+r; pair pc -> sDn cols (2pc, 2pc+1).
    auto downpair = [&](int r, int pc) {
        float accA = 0.f, accB = 0.f;
        #pragma unroll
        for (int i = 0; i < 5; ++i) {
            const float4 v0 = *(const float4*)&sIn[2 * r + i][4 * pc];
            const float4 v1 = *(const float4*)&sIn[2 * r + i][4 * pc + 4];
            accA += v0.x * kk[5*i+0] + v0.y * kk[5*i+1] + v0.z * kk[5*i+2] + v0.w * kk[5*i+3] + v1.x * kk[5*i+4];
            accB += v0.z * kk[5*i+0] + v0.w * kk[5*i+1] + v1.x * kk[5*i+2] + v1.y * kk[5*i+3] + v1.z * kk[5*i+4];
        }
        *(float2*)&sDn[r][2 * pc] = make_float2(accA, accB);
    };
    {
        constexpr int NPAIR = MQ * (DY + 2);       // main pairs (pow2 per row)
        for (int s = tid; s < NPAIR; s += 256) downpair(s >> LOG2MQ, s & (MQ - 1));
        if (tid < DY + 2) downpair(tid, MQ);       // halo pair: sDn cols DX, DX+1
    }
    __syncthreads();

    // ---------------- upsub phase (+ fold in down interior write) ----------------
    constexpr int NUP = MQ * DY;
    if (tid < NUP) {
        const int pq  = tid & (MQ - 1);
        const int pr  = tid >> LOG2MQ;
        const int gdy = dy0 + pr;
        // up boundary semantics: down[-1] -> down[1], down[H2] -> down[H2-1]
        const int r0 = (gdy == 0)      ? pr + 2 : pr;
        const int r2 = (gdy == H2 - 1) ? pr     : pr + 2;
        const int rows[3] = { r0, pr + 1, r2 };
        const bool leftE  = (dx0 == 0 && pq == 0);
        const bool rightE = (dx0 + 2 * pq + 1 == W2 - 1);

        float uee_a = 0, ueo_a = 0, uoe_a = 0, uoo_a = 0;
        float uee_b = 0, ueo_b = 0, uoe_b = 0, uoo_b = 0;
        #pragma unroll
        for (int i = 0; i < 3; ++i) {
            const float2 va = *(const float2*)&sDn[rows[i]][2 * pq];
            const float2 vb = *(const float2*)&sDn[rows[i]][2 * pq + 2];
            float aL = va.x, aC = va.y, aR = vb.x;
            float bL = va.y, bC = vb.x, bR = vb.y;
            if (leftE)  aL = aR;   // down[-1]  == down[1]
            if (rightE) bR = bC;   // down[W2]  == down[W2-1]
            uee_a += aL * kk[10*i+0] + aC * kk[10*i+2] + aR * kk[10*i+4];
            ueo_a += aC * kk[10*i+1] + aR * kk[10*i+3];
            uee_b += bL * kk[10*i+0] + bC * kk[10*i+2] + bR * kk[10*i+4];
            ueo_b += bC * kk[10*i+1] + bR * kk[10*i+3];
            if (i) {
                uoe_a += aL * kk[10*i-5] + aC * kk[10*i-3] + aR * kk[10*i-1];
                uoo_a += aC * kk[10*i-4] + aR * kk[10*i-2];
                uoe_b += bL * kk[10*i-5] + bC * kk[10*i-3] + bR * kk[10*i-1];
                uoo_b += bC * kk[10*i-4] + bR * kk[10*i-2];
            }
            if (i == 1) {  // center row values ARE the down interior: coalesced float2 store
                *(float2*)(down + (size_t)bc * H2 * W2 + (size_t)gdy * W2 + dx0 + 2 * pq)
                    = make_float2(aC, bC);
            }
        }

        const int ly = 2 * pr + 4;
        const int lx = 4 * pq + 4;
        const float4 c0 = *(const float4*)&sIn[ly][lx];
        const float4 c1 = *(const float4*)&sIn[ly + 1][lx];
        float* py = pyr + (size_t)bc * H * W;
        const size_t base = (size_t)(2 * gdy) * W + (2 * dx0 + 4 * pq);
        *(float4*)(py + base)     = make_float4(c0.x - uee_a, c0.y - ueo_a, c0.z - uee_b, c0.w - ueo_b);
        *(float4*)(py + base + W) = make_float4(c1.x - uoe_a, c1.y - uoo_a, c1.z - uoe_b, c1.w - uoo_b);
    }
}

// ---------------- fallback (no-workspace) kernels ----------------
__global__ __launch_bounds__(256) void down_kernel(
    const float* __restrict__ in, const float* __restrict__ kern,
    float* __restrict__ out, int H, int W)
{
    const int H2 = H >> 1, W2 = W >> 1;
    const int bc = blockIdx.z;
    const int c  = bc % C_;
    __shared__ float k[25];
    int tid = threadIdx.y * blockDim.x + threadIdx.x;
    if (tid < 25) k[tid] = kern[c * 25 + tid];
    __syncthreads();
    int x = blockIdx.x * blockDim.x + threadIdx.x;
    int y = blockIdx.y * blockDim.y + threadIdx.y;
    if (x >= W2 || y >= H2) return;
    const float* img = in + (size_t)bc * H * W;
    const int bx = 2 * x - 2, by = 2 * y - 2;
    float acc = 0.f;
    if (bx >= 0 && by >= 0 && bx + 4 < W && by + 4 < H) {
        const float* p = img + (size_t)by * W + bx;
        #pragma unroll
        for (int dy = 0; dy < 5; ++dy) {
            #pragma unroll
            for (int dx = 0; dx < 5; ++dx) acc += p[dx] * k[dy * 5 + dx];
            p += W;
        }
    } else {
        #pragma unroll
        for (int dy = 0; dy < 5; ++dy) {
            const float* row = img + (size_t)reflect101(by + dy, H) * W;
            #pragma unroll
            for (int dx = 0; dx < 5; ++dx) acc += row[reflect101(bx + dx, W)] * k[dy * 5 + dx];
        }
    }
    out[(size_t)bc * H2 * W2 + (size_t)y * W2 + x] = acc;
}

__global__ __launch_bounds__(256) void upsub_kernel(
    const float* __restrict__ cur, const float* __restrict__ kern,
    const float* __restrict__ down, float* __restrict__ pyr,
    int H2, int W2)
{
    const int H = H2 * 2, W = W2 * 2;
    const int bc = blockIdx.z;
    const int c  = bc % C_;
    __shared__ float k[25];
    int tid = threadIdx.y * blockDim.x + threadIdx.x;
    if (tid < 25) k[tid] = kern[c * 25 + tid];
    __syncthreads();
    int x2 = blockIdx.x * blockDim.x + threadIdx.x;
    int y2 = blockIdx.y * blockDim.y + threadIdx.y;
    if (x2 >= W2 || y2 >= H2) return;
    const float* dn = down + (size_t)bc * H2 * W2;
    const float* cu = cur  + (size_t)bc * H * W;
    float*       py = pyr  + (size_t)bc * H * W;
    const int xm = (x2 == 0)      ? 1      : x2 - 1;
    const int xp = (x2 == W2 - 1) ? W2 - 1 : x2 + 1;
    const int ym = (y2 == 0)      ? 1      : y2 - 1;
    const int yp = (y2 == H2 - 1) ? H2 - 1 : y2 + 1;
    float d[3][3];
    {
        const float* r0 = dn + (size_t)ym * W2;
        const float* r1 = dn + (size_t)y2 * W2;
        const float* r2 = dn + (size_t)yp * W2;
        d[0][0] = r0[xm]; d[0][1] = r0[x2]; d[0][2] = r0[xp];
        d[1][0] = r1[xm]; d[1][1] = r1[x2]; d[1][2] = r1[xp];
        d[2][0] = r2[xm]; d[2][1] = r2[x2]; d[2][2] = r2[xp];
    }
    float uee = 0.f, ueo = 0.f, uoe = 0.f, uoo = 0.f;
    #pragma unroll
    for (int i = 0; i < 3; ++i) {
        #pragma unroll
        for (int j = 0; j < 3; ++j) {
            const float v = d[i][j];
            uee += v * k[(2 * i) * 5 + 2 * j];
            if (j)      ueo += v * k[(2 * i) * 5 + 2 * j - 1];
            if (i)      uoe += v * k[(2 * i - 1) * 5 + 2 * j];
            if (i && j) uoo += v * k[(2 * i - 1) * 5 + 2 * j - 1];
        }
    }
    const int y = 2 * y2, x = 2 * x2;
    const float2 c0 = *(const float2*)(cu + (size_t)y       * W + x);
    const float2 c1 = *(const float2*)(cu + (size_t)(y + 1) * W + x);
    *(float2*)(py + (size_t)y       * W + x) = make_float2(c0.x - uee, c0.y - ueo);
    *(float2*)(py + (size_t)(y + 1) * W + x) = make_float2(c1.x - uoe, c1.y - uoo);
}

extern "C" void kernel_launch(void* const* d_in, const int* in_sizes, int n_in,
                              void* d_out, int out_size, void* d_ws, size_t ws_size,
                              hipStream_t stream) {
    const float* img  = (const float*)d_in[0];
    const float* kern = (const float*)d_in[1];
    float* out = (float*)d_out;

    const size_t n0 = (size_t)B_ * C_ * 512 * 512;
    const size_t n1 = (size_t)B_ * C_ * 256 * 256;
    const size_t n2 = (size_t)B_ * C_ * 128 * 128;

    float* pyr0  = out;
    float* pyr1  = out + n0;
    float* pyr2  = out + n0 + n1;
    float* down3 = out + n0 + n1 + n2;

    const int BC = B_ * C_;
    const size_t need = (n1 + n2) * sizeof(float);

    if (ws_size >= need) {
        float* down1 = (float*)d_ws;
        float* down2 = down1 + n1;
        // L0: 512 -> 256, tile 64x8 (down) per block
        lap_level_t<64, 8, 5><<<dim3(256 / 64, 256 / 8, BC), 256, 0, stream>>>(
            img, kern, down1, pyr0, 512, 512);
        // L1: 256 -> 128, tile 32x8
        lap_level_t<32, 8, 4><<<dim3(128 / 32, 128 / 8, BC), 256, 0, stream>>>(
            down1, kern, down2, pyr1, 256, 256);
        // L2: 128 -> 64, tile 32x8
        lap_level_t<32, 8, 4><<<dim3(64 / 32, 64 / 8, BC), 256, 0, stream>>>(
            down2, kern, down3, pyr2, 128, 128);
    } else {
        // fallback: R1 two-kernel in-place-safe scheme (down1/down2 parked in output slots)
        float* down1 = pyr1;
        float* down2 = pyr2;
        const dim3 blk(64, 4, 1);
        auto g2 = [&](int W2, int H2) { return dim3((W2 + 63) / 64, (H2 + 3) / 4, BC); };
        down_kernel <<<g2(256, 256), blk, 0, stream>>>(img, kern, down1, 512, 512);
        upsub_kernel<<<g2(256, 256), blk, 0, stream>>>(img, kern, down1, pyr0, 256, 256);
        down_kernel <<<g2(128, 128), blk, 0, stream>>>(down1, kern, down2, 256, 256);
        upsub_kernel<<<g2(128, 128), blk, 0, stream>>>(down1, kern, down2, pyr1, 128, 128);
        down_kernel <<<g2( 64,  64), blk, 0, stream>>>(down2, kern, down3, 128, 128);
        upsub_kernel<<<g2( 64,  64), blk, 0, stream>>>(down2, kern, down3, pyr2, 64, 64);
    }
}